// Round 9
// baseline (119.588 us; speedup 1.0000x reference)
//
#include <hip/hip_runtime.h>
#include <hip/hip_bf16.h>

typedef short s8v __attribute__((ext_vector_type(8)));      // 8 bf16 (4 VGPRs) MFMA A/B frag
typedef float f4v __attribute__((ext_vector_type(4)));      // MFMA C/D frag
typedef unsigned u4v __attribute__((ext_vector_type(4)));   // 4 packed bf16-pairs

__device__ __forceinline__ unsigned short f2bf(float x) {  // RTNE fp32->bf16 (prep only)
  unsigned u = __builtin_bit_cast(unsigned, x);
  u += 0x7fffu + ((u >> 16) & 1u);
  return (unsigned short)(u >> 16);
}
// fast pack: round-to-nearest-away bf16 pair via v_perm (3 VALU ops)
__device__ __forceinline__ unsigned pk2(float a, float b) {
  unsigned ua = __builtin_bit_cast(unsigned, a) + 0x8000u;
  unsigned ub = __builtin_bit_cast(unsigned, b) + 0x8000u;
  return __builtin_amdgcn_perm(ub, ua, 0x07060302u);  // {ub.hi16, ua.hi16}
}

// ---------------- prep: pack W1^T / W2^T as 16x16x32 bf16 A-fragments into ws --------
// W1f (8192): frag (h,ks): A[m=16h+l15][k=32ks+8q4+j]; k<13 -> W1 row k; k==13 -> b1;
//   14..15 -> 0; k>=16 -> W1 row k-3.
// W2f (16384): frag (h2,ks), K-permuted to match GEMM1-output register order:
//   k-slot 8q4+j (j<4) -> hidden 32ks+4q4+j ; (j>=4) -> hidden 32ks+16+4q4+(j-4).
__global__ void prep_kernel(const float* __restrict__ W1, const float* __restrict__ b1,
                            const float* __restrict__ W2, unsigned short* __restrict__ wsW) {
  int e = blockIdx.x * 256 + threadIdx.x;   // 96*256 = 24576 exactly
  if (e < 8192) {
    int frag = e >> 9, rem = e & 511, lane = rem >> 3, j = rem & 7;
    int h = frag >> 1, ks = frag & 1;
    int q4 = lane >> 4, l15 = lane & 15;
    int k = ks * 32 + q4 * 8 + j;
    int n = h * 16 + l15;
    float v;
    if (k < 13) v = W1[k * 128 + n];
    else if (k == 13) v = b1[n];
    else if (k < 16) v = 0.0f;
    else v = W1[(k - 3) * 128 + n];
    wsW[e] = f2bf(v);
  } else {
    int e2 = e - 8192;
    int frag = e2 >> 9, rem = e2 & 511, lane = rem >> 3, j = rem & 7;
    int h2 = frag >> 2, ks = frag & 3;
    int q4 = lane >> 4, l15 = lane & 15;
    int kd = (j < 4) ? (32 * ks + 4 * q4 + j) : (32 * ks + 16 + 4 * q4 + (j - 4));
    int n = h2 * 16 + l15;
    wsW[e] = f2bf(W2[kd * 128 + n]);
  }
}

// ---------------- main fused kernel ----------------
// 128 threads = 2 waves. WG = 64 rows (32 queries x 2 passes); each wave owns 32 rows
// as 2 row-tiles (rt). Grid = 8192. Small register footprint (~85 combined) targets
// ~5 waves/SIMD residency — R6/R8 showed the 124-VGPR variant parks at ~2-3.
// (x,2) bounds: tighter bounds trigger the gfx950 50/50 arch/acc split + scratch
// spill (R4/R5: reported VGPR == budget/2, WRITE_SIZE 66-700 MB).
__global__ __launch_bounds__(128, 2) void lisagon_main(
    const float* __restrict__ coord, const float* __restrict__ latent,
    const unsigned short* __restrict__ W1f, const unsigned short* __restrict__ W2f,
    const float* __restrict__ b2, const float* __restrict__ W3,
    const float* __restrict__ b3, float* __restrict__ out) {
  __shared__ __align__(16) unsigned short A1[64 * 64];   // 8 KB input tile
  __shared__ float AREA[64];

  const int t = threadIdx.x;
  const int lane = t & 63, wv = t >> 6;
  const int l15 = lane & 15, q4 = lane >> 4;

  // ---- phase 0: 2 threads per row, wave-uniform role split ----
  // role 0 (wave 0): searchsorted + PE (chunks 0,1) + prev latent (chunks 2,3) + AREA
  // role 1 (wave 1): searchsorted + self latent (chunks 4,5) + next latent (chunks 6,7)
  {
    const int r = t & 63;                     // local row 0..63
    const int role = t >> 6;                  // == wv (wave-uniform)
    const int Rg = blockIdx.x * 64 + r;
    const int gq = Rg >> 1, p = Rg & 1;       // p=0 -> vx=-2 pass, p=1 -> vx=0 pass
    const float co = coord[gq];
    float c = (co + (p ? 0.0f : -0.000244140625f)) + 1e-6f;  // vx*rx exact
    c = fminf(fmaxf(c, -1.0f + 1e-6f), 1.0f - 1e-6f);
    double u = ((double)c * 8192.0 + 8191.0) * 0.5;          // exact searchsorted
    int idx = (int)ceil(u);
    idx = min(max(idx, 0), 8191);

    uint4* A1v = (uint4*)A1;
    const float4* latv = (const float4*)(latent + (size_t)(gq >> 16) * (8192 * 16));

    if (role == 0) {
      // prev latent row -> chunks 2,3 (issue loads first)
      int lr = max(idx - 1, 0);
      float4 a = latv[lr * 4 + 0], b = latv[lr * 4 + 1];
      float4 cc = latv[lr * 4 + 2], d = latv[lr * 4 + 3];

      float qc = ((float)(2 * idx + 1) - 8192.0f) * (1.0f / 8192.0f);  // exact grid[idx]
      float rel = (co - qc) * 8192.0f;
      AREA[r] = fabsf(rel) + 1e-9f;
      // PE chunks 0,1
      float v[16];
      v[0] = rel;
      float f = rel;
#pragma unroll
      for (int i = 0; i < 6; i++) {
        v[1 + 2 * i] = __sinf(f);
        v[2 + 2 * i] = __cosf(f);
        f = f + f;                 // exact power-of-2 freqs
      }
      v[13] = 1.0f;                // bias-fold slot (W1f input dim 13 = b1)
      v[14] = 0.0f; v[15] = 0.0f;
#pragma unroll
      for (int ch = 0; ch < 2; ch++) {
        union { uint4 u4; unsigned us[4]; } pkv;
#pragma unroll
        for (int w = 0; w < 4; w++) pkv.us[w] = pk2(v[ch * 8 + 2 * w], v[ch * 8 + 2 * w + 1]);
        A1v[r * 8 + (ch ^ (r & 7))] = pkv.u4;
      }
      union { uint4 u4; unsigned us[4]; } p0, p1;
      p0.us[0] = pk2(a.x, a.y);  p0.us[1] = pk2(a.z, a.w);
      p0.us[2] = pk2(b.x, b.y);  p0.us[3] = pk2(b.z, b.w);
      p1.us[0] = pk2(cc.x, cc.y); p1.us[1] = pk2(cc.z, cc.w);
      p1.us[2] = pk2(d.x, d.y);  p1.us[3] = pk2(d.z, d.w);
      A1v[r * 8 + (2 ^ (r & 7))] = p0.u4;
      A1v[r * 8 + (3 ^ (r & 7))] = p1.u4;
    } else {
      // self latent -> chunks 4,5 ; next latent -> chunks 6,7
      int lr1 = min(idx + 1, 8191);
      float4 L[2][4];
#pragma unroll
      for (int w = 0; w < 4; w++) L[0][w] = latv[idx * 4 + w];
#pragma unroll
      for (int w = 0; w < 4; w++) L[1][w] = latv[lr1 * 4 + w];
#pragma unroll
      for (int s = 0; s < 2; s++) {
        union { uint4 u4; unsigned us[4]; } p0, p1;
        p0.us[0] = pk2(L[s][0].x, L[s][0].y); p0.us[1] = pk2(L[s][0].z, L[s][0].w);
        p0.us[2] = pk2(L[s][1].x, L[s][1].y); p0.us[3] = pk2(L[s][1].z, L[s][1].w);
        p1.us[0] = pk2(L[s][2].x, L[s][2].y); p1.us[1] = pk2(L[s][2].z, L[s][2].w);
        p1.us[2] = pk2(L[s][3].x, L[s][3].y); p1.us[3] = pk2(L[s][3].z, L[s][3].w);
        int ch0 = 4 + 2 * s;
        A1v[r * 8 + (ch0 ^ (r & 7))]       = p0.u4;
        A1v[r * 8 + ((ch0 + 1) ^ (r & 7))] = p1.u4;
      }
    }
  }
  __syncthreads();

  const s8v* W1fv = (const s8v*)W1f;
  const s8v* W2fv = (const s8v*)W2f;
  const s8v* A1s  = (const s8v*)A1;
  const int rbase = wv * 32;

  // ---- load the 4 input B-fragments (live across GEMM1) ----
  s8v Bf[2][2];
#pragma unroll
  for (int ks = 0; ks < 2; ks++)
#pragma unroll
    for (int rt = 0; rt < 2; rt++) {
      int row = rbase + rt * 16 + l15;
      Bf[ks][rt] = A1s[row * 8 + ((ks * 4 + q4) ^ (row & 7))];
    }

  // ---- GEMM1' (h-outer): one h-tile acc live; relu+pack DIRECTLY into bbv lanes ----
  // bbv[rt][ks] is GEMM2's B-fragment for K-chunk ks (K-permuted to match W2f):
  //   lane 2h'+half holds packed pair from GEMM1 output h = 2ks+h', half in {0,1}.
  u4v bbv[2][4];
#pragma unroll
  for (int h = 0; h < 8; h++) {
    f4v a[2];
#pragma unroll
    for (int rt = 0; rt < 2; rt++) a[rt] = (f4v){0.f, 0.f, 0.f, 0.f};
#pragma unroll
    for (int ks = 0; ks < 2; ks++) {
      s8v Af = W1fv[(h * 2 + ks) * 64 + lane];
#pragma unroll
      for (int rt = 0; rt < 2; rt++)
        a[rt] = __builtin_amdgcn_mfma_f32_16x16x32_bf16(Af, Bf[ks][rt], a[rt], 0, 0, 0);
    }
#pragma unroll
    for (int rt = 0; rt < 2; rt++) {
      bbv[rt][h >> 1][2 * (h & 1)]     = pk2(fmaxf(a[rt][0], 0.f), fmaxf(a[rt][1], 0.f));
      bbv[rt][h >> 1][2 * (h & 1) + 1] = pk2(fmaxf(a[rt][2], 0.f), fmaxf(a[rt][3], 0.f));
    }
  }

  // ---- GEMM2' (h2-outer): one h2-tile acc live; b2 as acc-init; consume into dot ----
  float s[2] = {0.f, 0.f};
#pragma unroll
  for (int h2 = 0; h2 < 8; h2++) {
    f4v a2[2];
    f4v b2v = ((const f4v*)b2)[h2 * 4 + q4];   // element i -> hidden2 16h2+4q4+i
    a2[0] = b2v; a2[1] = b2v;
#pragma unroll
    for (int ks = 0; ks < 4; ks++) {
      s8v Af = W2fv[(h2 * 4 + ks) * 64 + lane];
#pragma unroll
      for (int rt = 0; rt < 2; rt++)
        a2[rt] = __builtin_amdgcn_mfma_f32_16x16x32_bf16(
            Af, __builtin_bit_cast(s8v, bbv[rt][ks]), a2[rt], 0, 0, 0);
    }
    float4 w3v = ((const float4*)W3)[h2 * 4 + q4];
#pragma unroll
    for (int rt = 0; rt < 2; rt++) {
      s[rt] += fmaxf(a2[rt][0], 0.f) * w3v.x;
      s[rt] += fmaxf(a2[rt][1], 0.f) * w3v.y;
      s[rt] += fmaxf(a2[rt][2], 0.f) * w3v.z;
      s[rt] += fmaxf(a2[rt][3], 0.f) * w3v.w;
    }
  }

  // ---- layer-3 reduce + local-ensemble combine ----
  const float b3s = b3[0];
#pragma unroll
  for (int rt = 0; rt < 2; rt++) {
    float pred = s[rt];
    pred += __shfl_xor(pred, 16, 64);
    pred += __shfl_xor(pred, 32, 64);
    pred += b3s;
    float other = __shfl_xor(pred, 1, 64);   // (pass0, pass1) at adjacent l15
    if (q4 == 0 && (l15 & 1) == 0) {
      int row0 = rbase + rt * 16 + l15;
      float a0 = AREA[row0], a1 = AREA[row0 + 1];
      float tot = a0 + a1;
      // local_ensemble swap: pred(vx=-2)*a1/tot + pred(vx=0)*a0/tot
      out[(blockIdx.x * 64 + row0) >> 1] = pred * (a1 / tot) + other * (a0 / tot);
    }
  }
}

extern "C" void kernel_launch(void* const* d_in, const int* in_sizes, int n_in,
                              void* d_out, int out_size, void* d_ws, size_t ws_size,
                              hipStream_t stream) {
  const float* coord  = (const float*)d_in[0];
  const float* latent = (const float*)d_in[1];
  const float* W1 = (const float*)d_in[2];
  const float* b1 = (const float*)d_in[3];
  const float* W2 = (const float*)d_in[4];
  const float* b2 = (const float*)d_in[5];
  const float* W3 = (const float*)d_in[6];
  const float* b3 = (const float*)d_in[7];
  float* out = (float*)d_out;
  unsigned short* wsW = (unsigned short*)d_ws;   // [0,8192) W1f, [8192,24576) W2f

  prep_kernel<<<96, 256, 0, stream>>>(W1, b1, W2, wsW);
  lisagon_main<<<8192, 128, 0, stream>>>(coord, latent, wsW, wsW + 8192,
                                         b2, W3, b3, out);
}

// Round 10
// 107.760 us; speedup vs baseline: 1.1098x; 1.1098x over previous
//
#include <hip/hip_runtime.h>
#include <hip/hip_bf16.h>

typedef short s8v __attribute__((ext_vector_type(8)));      // 8 bf16 (4 VGPRs) MFMA A/B frag
typedef float f4v __attribute__((ext_vector_type(4)));      // MFMA C/D frag
typedef unsigned u4v __attribute__((ext_vector_type(4)));   // 4 packed bf16-pairs

__device__ __forceinline__ unsigned short f2bf(float x) {  // RTNE fp32->bf16 (prep only)
  unsigned u = __builtin_bit_cast(unsigned, x);
  u += 0x7fffu + ((u >> 16) & 1u);
  return (unsigned short)(u >> 16);
}
// pack 2 fp32 -> packed bf16 pair {lo=a, hi=b}
#if __has_builtin(__builtin_amdgcn_cvt_pk_bf16_f32)
__device__ __forceinline__ unsigned pk2(float a, float b) {
  return __builtin_bit_cast(unsigned, __builtin_amdgcn_cvt_pk_bf16_f32(a, b));  // 1 VALU op, RTNE
}
#else
__device__ __forceinline__ unsigned pk2(float a, float b) {  // 3 VALU ops, round-away
  unsigned ua = __builtin_bit_cast(unsigned, a) + 0x8000u;
  unsigned ub = __builtin_bit_cast(unsigned, b) + 0x8000u;
  return __builtin_amdgcn_perm(ub, ua, 0x07060302u);  // {ub.hi16, ua.hi16}
}
#endif

// ---------------- prep: pack W1^T / W2^T as 16x16x32 bf16 A-fragments into ws --------
// W1f (8192): frag (h,ks): A[m=16h+l15][k=32ks+8q4+j]; k<13 -> W1 row k; k==13 -> b1;
//   14..15 -> 0; k>=16 -> W1 row k-3.
// W2f (16384): frag (h2,ks), K-permuted to match GEMM1-output register order:
//   k-slot 8q4+j (j<4) -> hidden 32ks+4q4+j ; (j>=4) -> hidden 32ks+16+4q4+(j-4).
__global__ void prep_kernel(const float* __restrict__ W1, const float* __restrict__ b1,
                            const float* __restrict__ W2, unsigned short* __restrict__ wsW) {
  int e = blockIdx.x * 256 + threadIdx.x;   // 96*256 = 24576 exactly
  if (e < 8192) {
    int frag = e >> 9, rem = e & 511, lane = rem >> 3, j = rem & 7;
    int h = frag >> 1, ks = frag & 1;
    int q4 = lane >> 4, l15 = lane & 15;
    int k = ks * 32 + q4 * 8 + j;
    int n = h * 16 + l15;
    float v;
    if (k < 13) v = W1[k * 128 + n];
    else if (k == 13) v = b1[n];
    else if (k < 16) v = 0.0f;
    else v = W1[(k - 3) * 128 + n];
    wsW[e] = f2bf(v);
  } else {
    int e2 = e - 8192;
    int frag = e2 >> 9, rem = e2 & 511, lane = rem >> 3, j = rem & 7;
    int h2 = frag >> 2, ks = frag & 3;
    int q4 = lane >> 4, l15 = lane & 15;
    int kd = (j < 4) ? (32 * ks + 4 * q4 + j) : (32 * ks + 16 + 4 * q4 + (j - 4));
    int n = h2 * 16 + l15;
    wsW[e] = f2bf(W2[kd * 128 + n]);
  }
}

// ---------------- main fused kernel ----------------
// 512 threads = 8 waves. WG = 512 rows (256 queries x 2 passes); each wave owns 64 rows
// as 4 row-tiles (rt): every weight fragment feeds 4 MFMAs. Grid = 1024 -> 4 WG/CU
// sequential (vs R8's 16): amortizes the per-WG fixed chain (phase-0 gather latency +
// barrier + tails), which the R6/R8/R9 counter fits show dominates (per-CU execution is
// effectively serial per WG; extra residency didn't help in R9).
// (512,1) bounds: tighter bounds trigger the gfx950 50/50 arch/acc split + scratch
// spill (R4/R5: reported VGPR == budget/2, WRITE_SIZE 66-700 MB).
__global__ __launch_bounds__(512, 1) void lisagon_main(
    const float* __restrict__ coord, const float* __restrict__ latent,
    const unsigned short* __restrict__ W1f, const unsigned short* __restrict__ W2f,
    const float* __restrict__ b2, const float* __restrict__ W3,
    const float* __restrict__ b3, float* __restrict__ out) {
  __shared__ __align__(16) unsigned short A1[512 * 64];    // 64 KB input tile
  __shared__ float AREA[512];

  const int t = threadIdx.x;
  const int lane = t & 63, wv = t >> 6;
  const int l15 = lane & 15, q4 = lane >> 4;

  // ---- phase 0: one full input row per thread (no divergence) ----
  {
    const int r = t;                          // local row 0..511
    const int Rg = blockIdx.x * 512 + r;
    const int gq = Rg >> 1, p = Rg & 1;       // p=0 -> vx=-2 pass, p=1 -> vx=0 pass
    const float co = coord[gq];
    float c = (co + (p ? 0.0f : -0.000244140625f)) + 1e-6f;  // vx*rx exact
    c = fminf(fmaxf(c, -1.0f + 1e-6f), 1.0f - 1e-6f);
    double u = ((double)c * 8192.0 + 8191.0) * 0.5;          // exact searchsorted
    int idx = (int)ceil(u);
    idx = min(max(idx, 0), 8191);

    float qc = ((float)(2 * idx + 1) - 8192.0f) * (1.0f / 8192.0f);  // exact grid[idx]
    float rel = (co - qc) * 8192.0f;
    AREA[r] = fabsf(rel) + 1e-9f;

    uint4* A1v = (uint4*)A1;
    // latent chunks 2..7 (prev/self/next rows, 16 floats each) -- issue loads early
    const float4* latv = (const float4*)(latent + (size_t)(gq >> 16) * (8192 * 16));
    int rows3[3];
    rows3[0] = max(idx - 1, 0);
    rows3[1] = idx;
    rows3[2] = min(idx + 1, 8191);
    float4 L[3][4];
#pragma unroll
    for (int s = 0; s < 3; s++)
#pragma unroll
      for (int w = 0; w < 4; w++) L[s][w] = latv[rows3[s] * 4 + w];

    // PE chunks 0..1
    float v[16];
    v[0] = rel;
    float f = rel;
#pragma unroll
    for (int i = 0; i < 6; i++) {
      v[1 + 2 * i] = __sinf(f);
      v[2 + 2 * i] = __cosf(f);
      f = f + f;                 // exact power-of-2 freqs
    }
    v[13] = 1.0f;                // bias-fold slot (W1f input dim 13 = b1)
    v[14] = 0.0f; v[15] = 0.0f;
#pragma unroll
    for (int ch = 0; ch < 2; ch++) {
      union { uint4 u4; unsigned us[4]; } pkv;
#pragma unroll
      for (int w = 0; w < 4; w++) pkv.us[w] = pk2(v[ch * 8 + 2 * w], v[ch * 8 + 2 * w + 1]);
      A1v[r * 8 + (ch ^ (r & 7))] = pkv.u4;
    }
#pragma unroll
    for (int s = 0; s < 3; s++) {
      union { uint4 u4; unsigned us[4]; } p0, p1;
      p0.us[0] = pk2(L[s][0].x, L[s][0].y); p0.us[1] = pk2(L[s][0].z, L[s][0].w);
      p0.us[2] = pk2(L[s][1].x, L[s][1].y); p0.us[3] = pk2(L[s][1].z, L[s][1].w);
      p1.us[0] = pk2(L[s][2].x, L[s][2].y); p1.us[1] = pk2(L[s][2].z, L[s][2].w);
      p1.us[2] = pk2(L[s][3].x, L[s][3].y); p1.us[3] = pk2(L[s][3].z, L[s][3].w);
      int ch0 = 2 + 2 * s;
      A1v[r * 8 + (ch0 ^ (r & 7))]       = p0.u4;
      A1v[r * 8 + ((ch0 + 1) ^ (r & 7))] = p1.u4;
    }
  }
  __syncthreads();

  const s8v* W1fv = (const s8v*)W1f;
  const s8v* W2fv = (const s8v*)W2f;
  const s8v* A1s  = (const s8v*)A1;
  const int rbase = wv * 64;

  // ---- load all 8 input B-fragments (live across GEMM1) ----
  s8v Bf[2][4];
#pragma unroll
  for (int ks = 0; ks < 2; ks++)
#pragma unroll
    for (int rt = 0; rt < 4; rt++) {
      int row = rbase + rt * 16 + l15;
      Bf[ks][rt] = A1s[row * 8 + ((ks * 4 + q4) ^ (row & 7))];
    }

  // ---- GEMM1' (h-outer): one h-tile acc live; relu+pack DIRECTLY into bbv lanes ----
  // bbv[rt][ks] is GEMM2's B-fragment for K-chunk ks (K-permuted to match W2f):
  //   lane 2h'+half holds packed pair from GEMM1 output h = 2ks+h', half in {0,1}.
  u4v bbv[4][4];
#pragma unroll
  for (int h = 0; h < 8; h++) {
    f4v a[4];
#pragma unroll
    for (int rt = 0; rt < 4; rt++) a[rt] = (f4v){0.f, 0.f, 0.f, 0.f};
#pragma unroll
    for (int ks = 0; ks < 2; ks++) {
      s8v Af = W1fv[(h * 2 + ks) * 64 + lane];
#pragma unroll
      for (int rt = 0; rt < 4; rt++)
        a[rt] = __builtin_amdgcn_mfma_f32_16x16x32_bf16(Af, Bf[ks][rt], a[rt], 0, 0, 0);
    }
#pragma unroll
    for (int rt = 0; rt < 4; rt++) {
      bbv[rt][h >> 1][2 * (h & 1)]     = pk2(fmaxf(a[rt][0], 0.f), fmaxf(a[rt][1], 0.f));
      bbv[rt][h >> 1][2 * (h & 1) + 1] = pk2(fmaxf(a[rt][2], 0.f), fmaxf(a[rt][3], 0.f));
    }
  }

  // ---- GEMM2' (h2-outer): one h2-tile acc live; b2 as acc-init; consume into dot ----
  float s[4] = {0.f, 0.f, 0.f, 0.f};
#pragma unroll
  for (int h2 = 0; h2 < 8; h2++) {
    f4v a2[4];
    f4v b2v = ((const f4v*)b2)[h2 * 4 + q4];   // element i -> hidden2 16h2+4q4+i
#pragma unroll
    for (int rt = 0; rt < 4; rt++) a2[rt] = b2v;
#pragma unroll
    for (int ks = 0; ks < 4; ks++) {
      s8v Af = W2fv[(h2 * 4 + ks) * 64 + lane];
#pragma unroll
      for (int rt = 0; rt < 4; rt++)
        a2[rt] = __builtin_amdgcn_mfma_f32_16x16x32_bf16(
            Af, __builtin_bit_cast(s8v, bbv[rt][ks]), a2[rt], 0, 0, 0);
    }
    float4 w3v = ((const float4*)W3)[h2 * 4 + q4];
#pragma unroll
    for (int rt = 0; rt < 4; rt++) {
      s[rt] += fmaxf(a2[rt][0], 0.f) * w3v.x;
      s[rt] += fmaxf(a2[rt][1], 0.f) * w3v.y;
      s[rt] += fmaxf(a2[rt][2], 0.f) * w3v.z;
      s[rt] += fmaxf(a2[rt][3], 0.f) * w3v.w;
    }
  }

  // ---- layer-3 reduce + local-ensemble combine ----
  const float b3s = b3[0];
#pragma unroll
  for (int rt = 0; rt < 4; rt++) {
    float pred = s[rt];
    pred += __shfl_xor(pred, 16, 64);
    pred += __shfl_xor(pred, 32, 64);
    pred += b3s;
    float other = __shfl_xor(pred, 1, 64);   // (pass0, pass1) at adjacent l15
    if (q4 == 0 && (l15 & 1) == 0) {
      int row0 = rbase + rt * 16 + l15;
      float a0 = AREA[row0], a1 = AREA[row0 + 1];
      float tot = a0 + a1;
      // local_ensemble swap: pred(vx=-2)*a1/tot + pred(vx=0)*a0/tot
      out[(blockIdx.x * 512 + row0) >> 1] = pred * (a1 / tot) + other * (a0 / tot);
    }
  }
}

extern "C" void kernel_launch(void* const* d_in, const int* in_sizes, int n_in,
                              void* d_out, int out_size, void* d_ws, size_t ws_size,
                              hipStream_t stream) {
  const float* coord  = (const float*)d_in[0];
  const float* latent = (const float*)d_in[1];
  const float* W1 = (const float*)d_in[2];
  const float* b1 = (const float*)d_in[3];
  const float* W2 = (const float*)d_in[4];
  const float* b2 = (const float*)d_in[5];
  const float* W3 = (const float*)d_in[6];
  const float* b3 = (const float*)d_in[7];
  float* out = (float*)d_out;
  unsigned short* wsW = (unsigned short*)d_ws;   // [0,8192) W1f, [8192,24576) W2f

  prep_kernel<<<96, 256, 0, stream>>>(W1, b1, W2, wsW);
  lisagon_main<<<1024, 512, 0, stream>>>(coord, latent, wsW, wsW + 8192,
                                         b2, W3, b3, out);
}

// Round 11
// 100.401 us; speedup vs baseline: 1.1911x; 1.0733x over previous
//
#include <hip/hip_runtime.h>
#include <hip/hip_bf16.h>

typedef short s8v __attribute__((ext_vector_type(8)));      // 8 bf16 (4 VGPRs) MFMA A/B frag
typedef float f4v __attribute__((ext_vector_type(4)));      // MFMA C/D frag
typedef unsigned u4v __attribute__((ext_vector_type(4)));   // 4 packed bf16-pairs

__device__ __forceinline__ unsigned short f2bf(float x) {  // RTNE fp32->bf16 (prep only)
  unsigned u = __builtin_bit_cast(unsigned, x);
  u += 0x7fffu + ((u >> 16) & 1u);
  return (unsigned short)(u >> 16);
}
// pack 2 fp32 -> packed bf16 pair {lo=a, hi=b}
#if __has_builtin(__builtin_amdgcn_cvt_pk_bf16_f32)
__device__ __forceinline__ unsigned pk2(float a, float b) {
  return __builtin_bit_cast(unsigned, __builtin_amdgcn_cvt_pk_bf16_f32(a, b));
}
#else
__device__ __forceinline__ unsigned pk2(float a, float b) {  // 3 VALU ops, round-away
  unsigned ua = __builtin_bit_cast(unsigned, a) + 0x8000u;
  unsigned ub = __builtin_bit_cast(unsigned, b) + 0x8000u;
  return __builtin_amdgcn_perm(ub, ua, 0x07060302u);  // {ub.hi16, ua.hi16}
}
#endif

// async global->LDS DMA, 16 B per lane; LDS dest = wave-uniform base + lane*16
__device__ __forceinline__ void g2lds16(const void* g, void* l) {
  __builtin_amdgcn_global_load_lds(
      (const __attribute__((address_space(1))) unsigned*)g,
      (__attribute__((address_space(3))) unsigned*)l, 16, 0, 0);
}

// ---------------- prep: W1f/W2f fragment packs + latent->bf16 table ----------------
// ws layout (unsigned short): [0,8192) W1f, [8192,24576) W2f, [24576,24576+524288) latbf.
// W1f (8192): frag (h,ks): A[m=16h+l15][k=32ks+8q4+j]; k<13 -> W1 row k; k==13 -> b1;
//   14..15 -> 0; k>=16 -> W1 row k-3.
// W2f (16384): frag (h2,ks), K-permuted to match GEMM1-output register order:
//   k-slot 8q4+j (j<4) -> hidden 32ks+4q4+j ; (j>=4) -> hidden 32ks+16+4q4+(j-4).
__global__ void prep_kernel(const float* __restrict__ W1, const float* __restrict__ b1,
                            const float* __restrict__ W2, const float* __restrict__ latent,
                            unsigned short* __restrict__ wsW) {
  int e = blockIdx.x * 256 + threadIdx.x;   // 2144*256 = 548,864 = 24576 + 524288
  if (e < 8192) {
    int frag = e >> 9, rem = e & 511, lane = rem >> 3, j = rem & 7;
    int h = frag >> 1, ks = frag & 1;
    int q4 = lane >> 4, l15 = lane & 15;
    int k = ks * 32 + q4 * 8 + j;
    int n = h * 16 + l15;
    float v;
    if (k < 13) v = W1[k * 128 + n];
    else if (k == 13) v = b1[n];
    else if (k < 16) v = 0.0f;
    else v = W1[(k - 3) * 128 + n];
    wsW[e] = f2bf(v);
  } else if (e < 24576) {
    int e2 = e - 8192;
    int frag = e2 >> 9, rem = e2 & 511, lane = rem >> 3, j = rem & 7;
    int h2 = frag >> 2, ks = frag & 3;
    int q4 = lane >> 4, l15 = lane & 15;
    int kd = (j < 4) ? (32 * ks + 4 * q4 + j) : (32 * ks + 16 + 4 * q4 + (j - 4));
    int n = h2 * 16 + l15;
    wsW[e] = f2bf(W2[kd * 128 + n]);
  } else {
    int i = e - 24576;                      // 0 .. 524288-1 : latent -> bf16 (coalesced)
    wsW[e] = f2bf(latent[i]);
  }
}

// ---------------- main fused kernel ----------------
// 256 threads = 4 waves. WG = 256 rows (128 queries x 2 passes); each wave owns 64 rows
// as 4 row-tiles (rt): every weight fragment feeds 4 MFMAs. Grid = 2048.
// W2f staged to LDS via global_load_lds (DMA issued FIRST, overlaps phase-0 gather);
// remaining global weight set = W1f 16 KB -> L1-resident (no more 48 KB L1 thrash).
// LDS 65 KB -> 2 WG/CU. (256,2): tighter bounds trigger the gfx950 50/50 arch/acc
// split + scratch spill (R4/R5: reported VGPR == budget/2, WRITE_SIZE 66-700 MB).
__global__ __launch_bounds__(256, 2) void lisagon_main(
    const float* __restrict__ coord, const unsigned short* __restrict__ latbf,
    const unsigned short* __restrict__ W1f, const unsigned short* __restrict__ W2f,
    const float* __restrict__ b2, const float* __restrict__ W3,
    const float* __restrict__ b3, float* __restrict__ out) {
  __shared__ __align__(16) unsigned short A1[256 * 64];    // 32 KB input tile
  __shared__ __align__(16) unsigned short W2s[16384];      // 32 KB W2 fragments
  __shared__ float AREA[256];

  const int t = threadIdx.x;
  const int lane = t & 63, wv = t >> 6;
  const int l15 = lane & 15, q4 = lane >> 4;

  // ---- issue W2f -> LDS DMA first (overlaps phase-0's dependent gather chain) ----
#pragma unroll
  for (int it = 0; it < 8; it++) {
    int off = (it * 4 + wv) * 1024;          // bytes; wave-uniform LDS base
    g2lds16((const char*)W2f + off + lane * 16, (char*)W2s + off);
  }

  // ---- phase 0: one full input row per thread (no divergence) ----
  {
    const int r = t;                          // local row 0..255
    const int Rg = blockIdx.x * 256 + r;
    const int gq = Rg >> 1, p = Rg & 1;       // p=0 -> vx=-2 pass, p=1 -> vx=0 pass
    const float co = coord[gq];
    float c = (co + (p ? 0.0f : -0.000244140625f)) + 1e-6f;  // vx*rx exact
    c = fminf(fmaxf(c, -1.0f + 1e-6f), 1.0f - 1e-6f);
    double u = ((double)c * 8192.0 + 8191.0) * 0.5;          // exact searchsorted
    int idx = (int)ceil(u);
    idx = min(max(idx, 0), 8191);

    float qc = ((float)(2 * idx + 1) - 8192.0f) * (1.0f / 8192.0f);  // exact grid[idx]
    float rel = (co - qc) * 8192.0f;
    AREA[r] = fabsf(rel) + 1e-9f;

    uint4* A1v = (uint4*)A1;
    // latent chunks 2..7: 3 bf16 rows (prev/self/next), 32 B each -- no conversion
    const uint4* latv = (const uint4*)(latbf + (size_t)(gq >> 16) * (8192 * 16));
    int rows3[3];
    rows3[0] = max(idx - 1, 0);
    rows3[1] = idx;
    rows3[2] = min(idx + 1, 8191);
    uint4 L0[3], L1[3];
#pragma unroll
    for (int s = 0; s < 3; s++) {
      L0[s] = latv[rows3[s] * 2 + 0];
      L1[s] = latv[rows3[s] * 2 + 1];
    }

    // PE chunks 0..1
    float v[16];
    v[0] = rel;
    float f = rel;
#pragma unroll
    for (int i = 0; i < 6; i++) {
      v[1 + 2 * i] = __sinf(f);
      v[2 + 2 * i] = __cosf(f);
      f = f + f;                 // exact power-of-2 freqs
    }
    v[13] = 1.0f;                // bias-fold slot (W1f input dim 13 = b1)
    v[14] = 0.0f; v[15] = 0.0f;
#pragma unroll
    for (int ch = 0; ch < 2; ch++) {
      union { uint4 u4; unsigned us[4]; } pkv;
#pragma unroll
      for (int w = 0; w < 4; w++) pkv.us[w] = pk2(v[ch * 8 + 2 * w], v[ch * 8 + 2 * w + 1]);
      A1v[r * 8 + (ch ^ (r & 7))] = pkv.u4;
    }
#pragma unroll
    for (int s = 0; s < 3; s++) {
      int ch0 = 2 + 2 * s;
      A1v[r * 8 + (ch0 ^ (r & 7))]       = L0[s];
      A1v[r * 8 + ((ch0 + 1) ^ (r & 7))] = L1[s];
    }
  }
  __syncthreads();   // also drains the W2f DMA (vmcnt(0) before s_barrier)

  const s8v* W1fv = (const s8v*)W1f;
  const s8v* W2sv = (const s8v*)W2s;
  const s8v* A1s  = (const s8v*)A1;
  const int rbase = wv * 64;

  // ---- load all 8 input B-fragments (live across GEMM1) ----
  s8v Bf[2][4];
#pragma unroll
  for (int ks = 0; ks < 2; ks++)
#pragma unroll
    for (int rt = 0; rt < 4; rt++) {
      int row = rbase + rt * 16 + l15;
      Bf[ks][rt] = A1s[row * 8 + ((ks * 4 + q4) ^ (row & 7))];
    }

  // ---- GEMM1' (h-outer): one h-tile acc live; relu+pack DIRECTLY into bbv lanes ----
  // bbv[rt][ks] is GEMM2's B-fragment for K-chunk ks (K-permuted to match W2f):
  //   lane 2h'+half holds packed pair from GEMM1 output h = 2ks+h', half in {0,1}.
  u4v bbv[4][4];
#pragma unroll
  for (int h = 0; h < 8; h++) {
    f4v a[4];
#pragma unroll
    for (int rt = 0; rt < 4; rt++) a[rt] = (f4v){0.f, 0.f, 0.f, 0.f};
#pragma unroll
    for (int ks = 0; ks < 2; ks++) {
      s8v Af = W1fv[(h * 2 + ks) * 64 + lane];
#pragma unroll
      for (int rt = 0; rt < 4; rt++)
        a[rt] = __builtin_amdgcn_mfma_f32_16x16x32_bf16(Af, Bf[ks][rt], a[rt], 0, 0, 0);
    }
#pragma unroll
    for (int rt = 0; rt < 4; rt++) {
      bbv[rt][h >> 1][2 * (h & 1)]     = pk2(fmaxf(a[rt][0], 0.f), fmaxf(a[rt][1], 0.f));
      bbv[rt][h >> 1][2 * (h & 1) + 1] = pk2(fmaxf(a[rt][2], 0.f), fmaxf(a[rt][3], 0.f));
    }
  }

  // ---- GEMM2' (h2-outer, weights from LDS): b2 as acc-init; consume into dot ----
  float s[4] = {0.f, 0.f, 0.f, 0.f};
#pragma unroll
  for (int h2 = 0; h2 < 8; h2++) {
    f4v a2[4];
    f4v b2v = ((const f4v*)b2)[h2 * 4 + q4];   // element i -> hidden2 16h2+4q4+i
#pragma unroll
    for (int rt = 0; rt < 4; rt++) a2[rt] = b2v;
#pragma unroll
    for (int ks = 0; ks < 4; ks++) {
      s8v Af = W2sv[(h2 * 4 + ks) * 64 + lane];   // ds_read_b128, conflict-free
#pragma unroll
      for (int rt = 0; rt < 4; rt++)
        a2[rt] = __builtin_amdgcn_mfma_f32_16x16x32_bf16(
            Af, __builtin_bit_cast(s8v, bbv[rt][ks]), a2[rt], 0, 0, 0);
    }
    float4 w3v = ((const float4*)W3)[h2 * 4 + q4];
#pragma unroll
    for (int rt = 0; rt < 4; rt++) {
      s[rt] += fmaxf(a2[rt][0], 0.f) * w3v.x;
      s[rt] += fmaxf(a2[rt][1], 0.f) * w3v.y;
      s[rt] += fmaxf(a2[rt][2], 0.f) * w3v.z;
      s[rt] += fmaxf(a2[rt][3], 0.f) * w3v.w;
    }
  }

  // ---- layer-3 reduce + local-ensemble combine ----
  const float b3s = b3[0];
#pragma unroll
  for (int rt = 0; rt < 4; rt++) {
    float pred = s[rt];
    pred += __shfl_xor(pred, 16, 64);
    pred += __shfl_xor(pred, 32, 64);
    pred += b3s;
    float other = __shfl_xor(pred, 1, 64);   // (pass0, pass1) at adjacent l15
    if (q4 == 0 && (l15 & 1) == 0) {
      int row0 = rbase + rt * 16 + l15;
      float a0 = AREA[row0], a1 = AREA[row0 + 1];
      float tot = a0 + a1;
      // local_ensemble swap: pred(vx=-2)*a1/tot + pred(vx=0)*a0/tot
      out[(blockIdx.x * 256 + row0) >> 1] = pred * (a1 / tot) + other * (a0 / tot);
    }
  }
}

extern "C" void kernel_launch(void* const* d_in, const int* in_sizes, int n_in,
                              void* d_out, int out_size, void* d_ws, size_t ws_size,
                              hipStream_t stream) {
  const float* coord  = (const float*)d_in[0];
  const float* latent = (const float*)d_in[1];
  const float* W1 = (const float*)d_in[2];
  const float* b1 = (const float*)d_in[3];
  const float* W2 = (const float*)d_in[4];
  const float* b2 = (const float*)d_in[5];
  const float* W3 = (const float*)d_in[6];
  const float* b3 = (const float*)d_in[7];
  float* out = (float*)d_out;
  unsigned short* wsW = (unsigned short*)d_ws;   // W1f | W2f | latbf

  prep_kernel<<<2144, 256, 0, stream>>>(W1, b1, W2, latent, wsW);
  lisagon_main<<<2048, 256, 0, stream>>>(coord, wsW + 24576, wsW, wsW + 8192,
                                         b2, W3, b3, out);
}